// Round 1
// baseline (633.995 us; speedup 1.0000x reference)
//
#include <hip/hip_runtime.h>
#include <math.h>

#define D 128
#define HEADS 4
#define CH 32
#define LRELU 0.2f
#define LN_EPS 1e-5f

// ---------------- CSR build ----------------

__global__ void count_kernel(const int* __restrict__ dst, int* __restrict__ deg, int E) {
    int e = blockIdx.x * blockDim.x + threadIdx.x;
    if (e < E) atomicAdd(&deg[dst[e]], 1);
}

__global__ __launch_bounds__(1024) void scan_kernel(const int* __restrict__ deg,
                                                    int* __restrict__ off,
                                                    int* __restrict__ cur, int n) {
    const int t = threadIdx.x;
    const int chunk = (n + 1023) >> 10;
    const int start = t * chunk;
    int lsum = 0;
    for (int j = 0; j < chunk; ++j) {
        int idx = start + j;
        if (idx < n) lsum += deg[idx];
    }
    // inclusive scan of lsum within wave (64)
    int v = lsum;
    #pragma unroll
    for (int o = 1; o < 64; o <<= 1) {
        int u = __shfl_up(v, o);
        if ((t & 63) >= o) v += u;
    }
    __shared__ int wpre[16];
    if ((t & 63) == 63) wpre[t >> 6] = v;
    __syncthreads();
    if (t < 16) {
        int wv = wpre[t];
        #pragma unroll
        for (int o = 1; o < 16; o <<= 1) {
            int u = __shfl_up(wv, o);
            if (t >= o) wv += u;
        }
        wpre[t] = wv;
    }
    __syncthreads();
    int base = (t >= 64) ? wpre[(t >> 6) - 1] : 0;
    int run = base + v - lsum;   // exclusive prefix for this thread's chunk
    for (int j = 0; j < chunk; ++j) {
        int idx = start + j;
        if (idx < n) {
            off[idx] = run;
            cur[idx] = run;
            run += deg[idx];
        }
    }
    if (t == 1023) off[n] = run;
}

__global__ void scatter_kernel(const int* __restrict__ src, const int* __restrict__ dst,
                               int* __restrict__ cur, int* __restrict__ csrc, int E) {
    int e = blockIdx.x * blockDim.x + threadIdx.x;
    if (e < E) {
        int d = dst[e];
        int p = atomicAdd(&cur[d], 1);
        csrc[p] = src[e];
    }
}

// ---------------- Fused GEMM: X @ [Wl | Wr | Wres] (+bl,+br) ----------------
// M x 128 input, K=128, three 128-wide output panels.

#define GM_TM 64
#define GM_TN 64
#define GM_TK 16

__global__ __launch_bounds__(256) void gemm_fused(
    const float* __restrict__ X, int M,
    const float* __restrict__ Wl, const float* __restrict__ Wr, const float* __restrict__ Wres,
    const float* __restrict__ bl, const float* __restrict__ br,
    float* __restrict__ XL, float* __restrict__ XR, float* __restrict__ RESo)
{
    __shared__ float As[GM_TK][GM_TM + 4];
    __shared__ float Bs[GM_TK][GM_TN];

    const int tid = threadIdx.x;
    const int bm = blockIdx.x * GM_TM;
    const int bn = blockIdx.y * GM_TN;     // 0..383 in steps of 64
    const int seg = bn >> 7;               // 0: XL, 1: XR, 2: RES
    const int lc0 = bn & 127;

    const float* W;
    const float* bias;
    float* Out;
    if (seg == 0)      { W = Wl;   bias = bl;      Out = XL; }
    else if (seg == 1) { W = Wr;   bias = br;      Out = XR; }
    else               { W = Wres; bias = nullptr; Out = RESo; }

    const int tx = tid & 15;   // 16 col-groups of 4
    const int ty = tid >> 4;   // 16 row-groups of 4
    const int la_c = tid & 15; // k within A tile
    const int la_r = tid >> 4; // row 0..15 (x4 strided)
    const int lb_r = tid >> 6; // k row 0..3 (x4 strided)
    const int lb_c = tid & 63;

    float acc[4][4] = {};

    for (int k0 = 0; k0 < 128; k0 += GM_TK) {
        #pragma unroll
        for (int i = 0; i < 4; ++i) {
            int r = la_r + i * 16;
            int gr = bm + r;
            float v = (gr < M) ? X[(size_t)gr * D + k0 + la_c] : 0.f;
            As[la_c][r] = v;
        }
        #pragma unroll
        for (int i = 0; i < 4; ++i) {
            int kr = lb_r + i * 4;
            Bs[kr][lb_c] = W[(size_t)(k0 + kr) * D + lc0 + lb_c];
        }
        __syncthreads();
        #pragma unroll
        for (int kk = 0; kk < GM_TK; ++kk) {
            float a[4], b[4];
            #pragma unroll
            for (int i = 0; i < 4; ++i) a[i] = As[kk][ty * 4 + i];
            #pragma unroll
            for (int i = 0; i < 4; ++i) b[i] = Bs[kk][tx * 4 + i];
            #pragma unroll
            for (int i = 0; i < 4; ++i)
                #pragma unroll
                for (int j = 0; j < 4; ++j)
                    acc[i][j] = fmaf(a[i], b[j], acc[i][j]);
        }
        __syncthreads();
    }

    float4 bv = make_float4(0.f, 0.f, 0.f, 0.f);
    if (bias) bv = *(const float4*)&bias[lc0 + tx * 4];
    #pragma unroll
    for (int i = 0; i < 4; ++i) {
        int gr = bm + ty * 4 + i;
        if (gr >= M) continue;
        float4 o;
        o.x = acc[i][0] + bv.x;
        o.y = acc[i][1] + bv.y;
        o.z = acc[i][2] + bv.z;
        o.w = acc[i][3] + bv.w;
        *(float4*)&Out[(size_t)gr * D + lc0 + tx * 4] = o;
    }
}

// ---------------- Fused per-node: online-softmax GATv2 aggregation + residual + LN + ReLU --------
// one block (128 threads) per destination node; thread t owns feature t (head t/32, chan t%32)

__global__ __launch_bounds__(128) void gat_node(
    const float* __restrict__ XL, const float* __restrict__ XR, const float* __restrict__ RES,
    const float* __restrict__ att, const float* __restrict__ bias,
    const float* __restrict__ g, const float* __restrict__ be,
    const int* __restrict__ off, const int* __restrict__ csrc,
    float* __restrict__ OUT, int n)
{
    const int i = blockIdx.x;
    const int t = threadIdx.x;
    const float xr = XR[(size_t)i * D + t];
    const float at = att[t];

    // self-loop (reference appends it; order only affects fp rounding)
    float m, s, acc;
    {
        float xl = XL[(size_t)i * D + t];
        float v = xl + xr;
        v = v > 0.f ? v : LRELU * v;
        float p = v * at;
        #pragma unroll
        for (int o = 16; o >= 1; o >>= 1) p += __shfl_xor(p, o);
        m = p; s = 1.f; acc = xl;
    }

    const int e0 = off[i], e1 = off[i + 1];
    for (int e = e0; e < e1; ++e) {
        int src = csrc[e];
        float xl = XL[(size_t)src * D + t];
        float v = xl + xr;
        v = v > 0.f ? v : LRELU * v;
        float p = v * at;
        #pragma unroll
        for (int o = 16; o >= 1; o >>= 1) p += __shfl_xor(p, o);
        float nm = fmaxf(m, p);
        float so = __expf(m - nm);
        float w  = __expf(p - nm);
        s = s * so + w;
        acc = acc * so + w * xl;
        m = nm;
    }

    float row = acc / s + RES[(size_t)i * D + t] + bias[t];

    // LayerNorm over 128 (2 waves) + ReLU
    __shared__ float red[4];
    float sum = row, sq = row * row;
    #pragma unroll
    for (int o = 32; o >= 1; o >>= 1) {
        sum += __shfl_xor(sum, o);
        sq  += __shfl_xor(sq, o);
    }
    const int wv = t >> 6;
    if ((t & 63) == 0) { red[wv * 2] = sum; red[wv * 2 + 1] = sq; }
    __syncthreads();
    sum = red[0] + red[2];
    sq  = red[1] + red[3];
    float mu  = sum * (1.f / 128.f);
    float var = sq * (1.f / 128.f) - mu * mu;
    float y = (row - mu) * rsqrtf(var + LN_EPS) * g[t] + be[t];
    OUT[(size_t)i * D + t] = fmaxf(y, 0.f);
}

// ---------------- launch ----------------

extern "C" void kernel_launch(void* const* d_in, const int* in_sizes, int n_in,
                              void* d_out, int out_size, void* d_ws, size_t ws_size,
                              hipStream_t stream)
{
    const float* x    = (const float*)d_in[0];
    const int*   ei   = (const int*)d_in[1];
    const float* Wl0  = (const float*)d_in[2];
    const float* bl0  = (const float*)d_in[3];
    const float* Wr0  = (const float*)d_in[4];
    const float* br0  = (const float*)d_in[5];
    const float* att0 = (const float*)d_in[6];
    const float* Wres0= (const float*)d_in[7];
    const float* bias0= (const float*)d_in[8];
    const float* g0   = (const float*)d_in[9];
    const float* be0  = (const float*)d_in[10];
    const float* Wl1  = (const float*)d_in[11];
    const float* bl1  = (const float*)d_in[12];
    const float* Wr1  = (const float*)d_in[13];
    const float* br1  = (const float*)d_in[14];
    const float* att1 = (const float*)d_in[15];
    const float* Wres1= (const float*)d_in[16];
    const float* bias1= (const float*)d_in[17];
    const float* g1   = (const float*)d_in[18];
    const float* be1  = (const float*)d_in[19];

    const int N = in_sizes[0] / D;
    const int E = in_sizes[1] / 2;

    char* w = (char*)d_ws;
    float* XL   = (float*)w; w += (size_t)N * D * 4;
    float* XR   = (float*)w; w += (size_t)N * D * 4;
    float* RES  = (float*)w; w += (size_t)N * D * 4;
    float* Hbuf = (float*)w; w += (size_t)N * D * 4;
    int* deg  = (int*)w; w += (size_t)N * 4;
    int* off  = (int*)w; w += (size_t)(N + 1) * 4;
    int* cur  = (int*)w; w += (size_t)N * 4;
    int* csrc = (int*)w; w += (size_t)E * 4;

    const int* srcp = ei;
    const int* dstp = ei + E;

    // CSR by destination (built once; shared by both layers)
    hipMemsetAsync(deg, 0, (size_t)N * 4, stream);
    count_kernel<<<(E + 255) / 256, 256, 0, stream>>>(dstp, deg, E);
    scan_kernel<<<1, 1024, 0, stream>>>(deg, off, cur, N);
    scatter_kernel<<<(E + 255) / 256, 256, 0, stream>>>(srcp, dstp, cur, csrc, E);

    dim3 ggrid((N + GM_TM - 1) / GM_TM, 3 * D / GM_TN);

    // Layer 0
    gemm_fused<<<ggrid, 256, 0, stream>>>(x, N, Wl0, Wr0, Wres0, bl0, br0, XL, XR, RES);
    gat_node<<<N, 128, 0, stream>>>(XL, XR, RES, att0, bias0, g0, be0, off, csrc, Hbuf, N);
    // Layer 1
    gemm_fused<<<ggrid, 256, 0, stream>>>(Hbuf, N, Wl1, Wr1, Wres1, bl1, br1, XL, XR, RES);
    gat_node<<<N, 128, 0, stream>>>(XL, XR, RES, att1, bias1, g1, be1, off, csrc, (float*)d_out, N);
}

// Round 2
// 556.730 us; speedup vs baseline: 1.1388x; 1.1388x over previous
//
#include <hip/hip_runtime.h>
#include <math.h>

#define D 128
#define LRELU 0.2f
#define LN_EPS 1e-5f

// ---------------- CSR build (self-loops folded in: E' = E + N) ----------------

__global__ void count_kernel(const int* __restrict__ dst, int* __restrict__ deg, int E, int N) {
    int e = blockIdx.x * blockDim.x + threadIdx.x;
    if (e < E + N) atomicAdd(&deg[e < E ? dst[e] : e - E], 1);
}

__global__ __launch_bounds__(1024) void scan_kernel(const int* __restrict__ deg,
                                                    int* __restrict__ off,
                                                    int* __restrict__ cur, int n) {
    const int t = threadIdx.x;
    const int chunk = (n + 1023) >> 10;
    const int start = t * chunk;
    int lsum = 0;
    for (int j = 0; j < chunk; ++j) {
        int idx = start + j;
        if (idx < n) lsum += deg[idx];
    }
    int v = lsum;
    #pragma unroll
    for (int o = 1; o < 64; o <<= 1) {
        int u = __shfl_up(v, o);
        if ((t & 63) >= o) v += u;
    }
    __shared__ int wpre[16];
    if ((t & 63) == 63) wpre[t >> 6] = v;
    __syncthreads();
    if (t < 16) {
        int wv = wpre[t];
        #pragma unroll
        for (int o = 1; o < 16; o <<= 1) {
            int u = __shfl_up(wv, o);
            if (t >= o) wv += u;
        }
        wpre[t] = wv;
    }
    __syncthreads();
    int base = (t >= 64) ? wpre[(t >> 6) - 1] : 0;
    int run = base + v - lsum;
    for (int j = 0; j < chunk; ++j) {
        int idx = start + j;
        if (idx < n) {
            off[idx] = run;
            cur[idx] = run;
            run += deg[idx];
        }
    }
    if (t == 1023) off[n] = run;
}

__global__ void scatter_kernel(const int* __restrict__ src, const int* __restrict__ dst,
                               int* __restrict__ cur, int* __restrict__ csrc, int E, int N) {
    int e = blockIdx.x * blockDim.x + threadIdx.x;
    if (e < E + N) {
        int d  = (e < E) ? dst[e] : e - E;
        int sc = (e < E) ? src[e] : e - E;
        int p = atomicAdd(&cur[d], 1);
        csrc[p] = sc;
    }
}

// ---------------- Fused GEMM: X @ [Wl | Wr | Wres] (+bl,+br) ----------------
// 128x128 block tile, 8x8 per-thread microtile, K-transposed LDS tiles.

#define TM 128
#define TK 16

__global__ __launch_bounds__(256) void gemm_fused(
    const float* __restrict__ X, int M,
    const float* __restrict__ Wl, const float* __restrict__ Wr, const float* __restrict__ Wres,
    const float* __restrict__ bl, const float* __restrict__ br,
    float* __restrict__ XL, float* __restrict__ XR, float* __restrict__ RESo)
{
    __shared__ float As[TK][TM + 4];    // [k][row]
    __shared__ float Bs[TK][128 + 16];  // [k][col-skewed]

    const int tid = threadIdx.x;
    const int bm = blockIdx.x * TM;
    const int seg = blockIdx.y;   // 0: XL, 1: XR, 2: RES

    const float* W;
    const float* bias;
    float* Out;
    if (seg == 0)      { W = Wl;   bias = bl;      Out = XL; }
    else if (seg == 1) { W = Wr;   bias = br;      Out = XR; }
    else               { W = Wres; bias = nullptr; Out = RESo; }

    const int tx = tid & 15;   // col group of 8
    const int ty = tid >> 4;   // row group of 8
    const int bc = tx * 8 + (tx >> 2) * 4;  // skewed LDS col base

    float acc[8][8] = {};

    for (int k0 = 0; k0 < 128; k0 += TK) {
        #pragma unroll
        for (int j = 0; j < 2; ++j) {
            int id = tid + 256 * j;
            int r = id >> 2;
            int kc = (id & 3) * 4;
            int gr = bm + r;
            float4 v = make_float4(0.f, 0.f, 0.f, 0.f);
            if (gr < M) v = *(const float4*)&X[(size_t)gr * D + k0 + kc];
            As[kc + 0][r] = v.x;
            As[kc + 1][r] = v.y;
            As[kc + 2][r] = v.z;
            As[kc + 3][r] = v.w;
        }
        #pragma unroll
        for (int j = 0; j < 2; ++j) {
            int id = tid + 256 * j;
            int k = id >> 5;
            int c = (id & 31) * 4;
            float4 v = *(const float4*)&W[(size_t)(k0 + k) * D + c];
            int cs = c + (c >> 5) * 4;
            *(float4*)&Bs[k][cs] = v;
        }
        __syncthreads();
        #pragma unroll
        for (int kk = 0; kk < TK; ++kk) {
            float4 a0 = *(const float4*)&As[kk][ty * 8];
            float4 a1 = *(const float4*)&As[kk][ty * 8 + 4];
            float4 b0 = *(const float4*)&Bs[kk][bc];
            float4 b1 = *(const float4*)&Bs[kk][bc + 4];
            float a[8] = {a0.x, a0.y, a0.z, a0.w, a1.x, a1.y, a1.z, a1.w};
            float b[8] = {b0.x, b0.y, b0.z, b0.w, b1.x, b1.y, b1.z, b1.w};
            #pragma unroll
            for (int i = 0; i < 8; ++i)
                #pragma unroll
                for (int jj = 0; jj < 8; ++jj)
                    acc[i][jj] = fmaf(a[i], b[jj], acc[i][jj]);
        }
        __syncthreads();
    }

    float4 bv0 = make_float4(0.f, 0.f, 0.f, 0.f);
    float4 bv1 = make_float4(0.f, 0.f, 0.f, 0.f);
    if (bias) {
        bv0 = *(const float4*)&bias[tx * 8];
        bv1 = *(const float4*)&bias[tx * 8 + 4];
    }
    #pragma unroll
    for (int i = 0; i < 8; ++i) {
        int gr = bm + ty * 8 + i;
        if (gr >= M) continue;
        float4 o0, o1;
        o0.x = acc[i][0] + bv0.x; o0.y = acc[i][1] + bv0.y;
        o0.z = acc[i][2] + bv0.z; o0.w = acc[i][3] + bv0.w;
        o1.x = acc[i][4] + bv1.x; o1.y = acc[i][5] + bv1.y;
        o1.z = acc[i][6] + bv1.z; o1.w = acc[i][7] + bv1.w;
        *(float4*)&Out[(size_t)gr * D + tx * 8]     = o0;
        *(float4*)&Out[(size_t)gr * D + tx * 8 + 4] = o1;
    }
}

// ---------------- Fused per-node GATv2: online softmax, 4-edge batches ----------------

__global__ __launch_bounds__(128) void gat_node(
    const float* __restrict__ XL, const float* __restrict__ XR, const float* __restrict__ RES,
    const float* __restrict__ att, const float* __restrict__ bias,
    const float* __restrict__ g, const float* __restrict__ be,
    const int* __restrict__ off, const int* __restrict__ csrc,
    float* __restrict__ OUT, int n)
{
    const int i = blockIdx.x;
    const int t = threadIdx.x;
    const float xr = XR[(size_t)i * D + t];
    const float at = att[t];

    float m = -1e30f, s = 0.f, acc = 0.f;

    const int e0 = off[i], e1 = off[i + 1];
    int e = e0;
    for (; e + 4 <= e1; e += 4) {
        int s0 = csrc[e], s1 = csrc[e + 1], s2 = csrc[e + 2], s3 = csrc[e + 3];
        float x0 = XL[(size_t)s0 * D + t];
        float x1 = XL[(size_t)s1 * D + t];
        float x2 = XL[(size_t)s2 * D + t];
        float x3 = XL[(size_t)s3 * D + t];
        float v0 = x0 + xr, v1 = x1 + xr, v2 = x2 + xr, v3 = x3 + xr;
        float p0 = fmaxf(v0, LRELU * v0) * at;
        float p1 = fmaxf(v1, LRELU * v1) * at;
        float p2 = fmaxf(v2, LRELU * v2) * at;
        float p3 = fmaxf(v3, LRELU * v3) * at;
        #pragma unroll
        for (int o = 16; o >= 1; o >>= 1) {
            p0 += __shfl_xor(p0, o);
            p1 += __shfl_xor(p1, o);
            p2 += __shfl_xor(p2, o);
            p3 += __shfl_xor(p3, o);
        }
        float pmax = fmaxf(fmaxf(p0, p1), fmaxf(p2, p3));
        float nm = fmaxf(m, pmax);
        float so = __expf(m - nm);
        float w0 = __expf(p0 - nm), w1 = __expf(p1 - nm);
        float w2 = __expf(p2 - nm), w3 = __expf(p3 - nm);
        s = s * so + ((w0 + w1) + (w2 + w3));
        acc = acc * so + (((w0 * x0 + w1 * x1) + (w2 * x2 + w3 * x3)));
        m = nm;
    }
    for (; e < e1; ++e) {
        int src = csrc[e];
        float xl = XL[(size_t)src * D + t];
        float v = xl + xr;
        float p = fmaxf(v, LRELU * v) * at;
        #pragma unroll
        for (int o = 16; o >= 1; o >>= 1) p += __shfl_xor(p, o);
        float nm = fmaxf(m, p);
        float so = __expf(m - nm);
        float w  = __expf(p - nm);
        s = s * so + w;
        acc = acc * so + w * xl;
        m = nm;
    }

    float row = acc / s + RES[(size_t)i * D + t] + bias[t];

    // LayerNorm over 128 (2 waves) + ReLU
    __shared__ float red[4];
    float sum = row, sq = row * row;
    #pragma unroll
    for (int o = 32; o >= 1; o >>= 1) {
        sum += __shfl_xor(sum, o);
        sq  += __shfl_xor(sq, o);
    }
    const int wv = t >> 6;
    if ((t & 63) == 0) { red[wv * 2] = sum; red[wv * 2 + 1] = sq; }
    __syncthreads();
    sum = red[0] + red[2];
    sq  = red[1] + red[3];
    float mu  = sum * (1.f / 128.f);
    float var = sq * (1.f / 128.f) - mu * mu;
    float y = (row - mu) * rsqrtf(var + LN_EPS) * g[t] + be[t];
    OUT[(size_t)i * D + t] = fmaxf(y, 0.f);
}

// ---------------- launch ----------------

extern "C" void kernel_launch(void* const* d_in, const int* in_sizes, int n_in,
                              void* d_out, int out_size, void* d_ws, size_t ws_size,
                              hipStream_t stream)
{
    const float* x    = (const float*)d_in[0];
    const int*   ei   = (const int*)d_in[1];
    const float* Wl0  = (const float*)d_in[2];
    const float* bl0  = (const float*)d_in[3];
    const float* Wr0  = (const float*)d_in[4];
    const float* br0  = (const float*)d_in[5];
    const float* att0 = (const float*)d_in[6];
    const float* Wres0= (const float*)d_in[7];
    const float* bias0= (const float*)d_in[8];
    const float* g0   = (const float*)d_in[9];
    const float* be0  = (const float*)d_in[10];
    const float* Wl1  = (const float*)d_in[11];
    const float* bl1  = (const float*)d_in[12];
    const float* Wr1  = (const float*)d_in[13];
    const float* br1  = (const float*)d_in[14];
    const float* att1 = (const float*)d_in[15];
    const float* Wres1= (const float*)d_in[16];
    const float* bias1= (const float*)d_in[17];
    const float* g1   = (const float*)d_in[18];
    const float* be1  = (const float*)d_in[19];

    const int N = in_sizes[0] / D;
    const int E = in_sizes[1] / 2;
    const int E2 = E + N;

    char* w = (char*)d_ws;
    float* XL   = (float*)w; w += (size_t)N * D * 4;
    float* XR   = (float*)w; w += (size_t)N * D * 4;
    float* RES  = (float*)w; w += (size_t)N * D * 4;
    float* Hbuf = (float*)w; w += (size_t)N * D * 4;
    int* deg  = (int*)w; w += (size_t)N * 4;
    int* off  = (int*)w; w += (size_t)(N + 1) * 4;
    int* cur  = (int*)w; w += (size_t)N * 4;
    int* csrc = (int*)w; w += (size_t)E2 * 4;

    const int* srcp = ei;
    const int* dstp = ei + E;

    hipMemsetAsync(deg, 0, (size_t)N * 4, stream);
    count_kernel<<<(E2 + 255) / 256, 256, 0, stream>>>(dstp, deg, E, N);
    scan_kernel<<<1, 1024, 0, stream>>>(deg, off, cur, N);
    scatter_kernel<<<(E2 + 255) / 256, 256, 0, stream>>>(srcp, dstp, cur, csrc, E, N);

    dim3 ggrid((N + TM - 1) / TM, 3);

    gemm_fused<<<ggrid, 256, 0, stream>>>(x, N, Wl0, Wr0, Wres0, bl0, br0, XL, XR, RES);
    gat_node<<<N, 128, 0, stream>>>(XL, XR, RES, att0, bias0, g0, be0, off, csrc, Hbuf, N);
    gemm_fused<<<ggrid, 256, 0, stream>>>(Hbuf, N, Wl1, Wr1, Wres1, bl1, br1, XL, XR, RES);
    gat_node<<<N, 128, 0, stream>>>(XL, XR, RES, att1, bias1, g1, be1, off, csrc, (float*)d_out, N);
}

// Round 3
// 372.694 us; speedup vs baseline: 1.7011x; 1.4938x over previous
//
#include <hip/hip_runtime.h>
#include <math.h>

#define D 128
#define LRELU 0.2f
#define LN_EPS 1e-5f

// ---------------- CSR build (self-loops folded in: E' = E + N) ----------------

__global__ void count_kernel(const int* __restrict__ dst, int* __restrict__ deg, int E, int N) {
    int e = blockIdx.x * blockDim.x + threadIdx.x;
    if (e < E + N) atomicAdd(&deg[e < E ? dst[e] : e - E], 1);
}

#define SCB 256

// block partial sums of deg
__global__ __launch_bounds__(SCB) void partial_kernel(const int* __restrict__ deg,
                                                      int* __restrict__ bsum, int n) {
    int i = blockIdx.x * SCB + threadIdx.x;
    int v = (i < n) ? deg[i] : 0;
    #pragma unroll
    for (int o = 32; o >= 1; o >>= 1) v += __shfl_xor(v, o);
    __shared__ int ws[4];
    if ((threadIdx.x & 63) == 0) ws[threadIdx.x >> 6] = v;
    __syncthreads();
    if (threadIdx.x == 0) bsum[blockIdx.x] = ws[0] + ws[1] + ws[2] + ws[3];
}

// in-place exclusive scan of block sums (nb <= 256)
__global__ __launch_bounds__(SCB) void scan_bsum_kernel(int* __restrict__ bsum, int nb) {
    int t = threadIdx.x;
    int v = (t < nb) ? bsum[t] : 0;
    int incl = v;
    #pragma unroll
    for (int o = 1; o < 64; o <<= 1) {
        int u = __shfl_up(incl, o);
        if ((t & 63) >= o) incl += u;
    }
    __shared__ int wp[4];
    if ((t & 63) == 63) wp[t >> 6] = incl;
    __syncthreads();
    int add = 0;
    for (int k = 0; k < (t >> 6); ++k) add += wp[k];
    incl += add;
    if (t < nb) bsum[t] = incl - v;   // exclusive
}

// per-block exclusive scan + block offset -> off, cur
__global__ __launch_bounds__(SCB) void write_off_kernel(const int* __restrict__ deg,
                                                        const int* __restrict__ boff,
                                                        int* __restrict__ off,
                                                        int* __restrict__ cur, int n) {
    int t = threadIdx.x;
    int i = blockIdx.x * SCB + t;
    int v = (i < n) ? deg[i] : 0;
    int incl = v;
    #pragma unroll
    for (int o = 1; o < 64; o <<= 1) {
        int u = __shfl_up(incl, o);
        if ((t & 63) >= o) incl += u;
    }
    __shared__ int wp[4];
    if ((t & 63) == 63) wp[t >> 6] = incl;
    __syncthreads();
    int add = boff[blockIdx.x];
    for (int k = 0; k < (t >> 6); ++k) add += wp[k];
    int excl = add + incl - v;
    if (i < n) { off[i] = excl; cur[i] = excl; }
    if (i == n - 1) off[n] = excl + v;
}

__global__ void scatter_kernel(const int* __restrict__ src, const int* __restrict__ dst,
                               int* __restrict__ cur, int* __restrict__ csrc, int E, int N) {
    int e = blockIdx.x * blockDim.x + threadIdx.x;
    if (e < E + N) {
        int d  = (e < E) ? dst[e] : e - E;
        int sc = (e < E) ? src[e] : e - E;
        int p = atomicAdd(&cur[d], 1);
        csrc[p] = sc;
    }
}

// ---------------- Fused GEMM: X @ [Wl | Wr | Wres] (+bl,+br) ----------------

#define TM 128
#define TK 16

__global__ __launch_bounds__(256) void gemm_fused(
    const float* __restrict__ X, int M,
    const float* __restrict__ Wl, const float* __restrict__ Wr, const float* __restrict__ Wres,
    const float* __restrict__ bl, const float* __restrict__ br,
    float* __restrict__ XL, float* __restrict__ XR, float* __restrict__ RESo)
{
    __shared__ float As[TK][TM + 4];    // [k][row]
    __shared__ float Bs[TK][128 + 16];  // [k][col-skewed]

    const int tid = threadIdx.x;
    const int bm = blockIdx.x * TM;
    const int seg = blockIdx.y;   // 0: XL, 1: XR, 2: RES

    const float* W;
    const float* bias;
    float* Out;
    if (seg == 0)      { W = Wl;   bias = bl;      Out = XL; }
    else if (seg == 1) { W = Wr;   bias = br;      Out = XR; }
    else               { W = Wres; bias = nullptr; Out = RESo; }

    const int tx = tid & 15;
    const int ty = tid >> 4;
    const int bc = tx * 8 + (tx >> 2) * 4;

    float acc[8][8] = {};

    for (int k0 = 0; k0 < 128; k0 += TK) {
        #pragma unroll
        for (int j = 0; j < 2; ++j) {
            int id = tid + 256 * j;
            int r = id >> 2;
            int kc = (id & 3) * 4;
            int gr = bm + r;
            float4 v = make_float4(0.f, 0.f, 0.f, 0.f);
            if (gr < M) v = *(const float4*)&X[(size_t)gr * D + k0 + kc];
            As[kc + 0][r] = v.x;
            As[kc + 1][r] = v.y;
            As[kc + 2][r] = v.z;
            As[kc + 3][r] = v.w;
        }
        #pragma unroll
        for (int j = 0; j < 2; ++j) {
            int id = tid + 256 * j;
            int k = id >> 5;
            int c = (id & 31) * 4;
            float4 v = *(const float4*)&W[(size_t)(k0 + k) * D + c];
            int cs = c + (c >> 5) * 4;
            *(float4*)&Bs[k][cs] = v;
        }
        __syncthreads();
        #pragma unroll
        for (int kk = 0; kk < TK; ++kk) {
            float4 a0 = *(const float4*)&As[kk][ty * 8];
            float4 a1 = *(const float4*)&As[kk][ty * 8 + 4];
            float4 b0 = *(const float4*)&Bs[kk][bc];
            float4 b1 = *(const float4*)&Bs[kk][bc + 4];
            float a[8] = {a0.x, a0.y, a0.z, a0.w, a1.x, a1.y, a1.z, a1.w};
            float b[8] = {b0.x, b0.y, b0.z, b0.w, b1.x, b1.y, b1.z, b1.w};
            #pragma unroll
            for (int i = 0; i < 8; ++i)
                #pragma unroll
                for (int jj = 0; jj < 8; ++jj)
                    acc[i][jj] = fmaf(a[i], b[jj], acc[i][jj]);
        }
        __syncthreads();
    }

    float4 bv0 = make_float4(0.f, 0.f, 0.f, 0.f);
    float4 bv1 = make_float4(0.f, 0.f, 0.f, 0.f);
    if (bias) {
        bv0 = *(const float4*)&bias[tx * 8];
        bv1 = *(const float4*)&bias[tx * 8 + 4];
    }
    #pragma unroll
    for (int i = 0; i < 8; ++i) {
        int gr = bm + ty * 8 + i;
        if (gr >= M) continue;
        float4 o0, o1;
        o0.x = acc[i][0] + bv0.x; o0.y = acc[i][1] + bv0.y;
        o0.z = acc[i][2] + bv0.z; o0.w = acc[i][3] + bv0.w;
        o1.x = acc[i][4] + bv1.x; o1.y = acc[i][5] + bv1.y;
        o1.z = acc[i][6] + bv1.z; o1.w = acc[i][7] + bv1.w;
        *(float4*)&Out[(size_t)gr * D + tx * 8]     = o0;
        *(float4*)&Out[(size_t)gr * D + tx * 8 + 4] = o1;
    }
}

// ---------------- Fused per-node GATv2: wave-per-node, float2 lanes ----------------
// lane l owns channels 2l, 2l+1; head = 16-lane group; 4-edge batches.

#define WPB 4

__global__ __launch_bounds__(64 * WPB) void gat_node(
    const float* __restrict__ XL, const float* __restrict__ XR, const float* __restrict__ RES,
    const float* __restrict__ att, const float* __restrict__ bias,
    const float* __restrict__ g, const float* __restrict__ be,
    const int* __restrict__ off, const int* __restrict__ csrc,
    float* __restrict__ OUT, int n)
{
    const int lane = threadIdx.x & 63;
    const int i = blockIdx.x * WPB + (threadIdx.x >> 6);
    if (i >= n) return;

    const int f = lane * 2;
    const float2 xr = *(const float2*)&XR[(size_t)i * D + f];
    const float2 at = *(const float2*)&att[f];

    float m = -1e30f, s = 0.f;
    float ax = 0.f, ay = 0.f;

    const int e0 = off[i], e1 = off[i + 1];
    int e = e0;
    for (; e + 4 <= e1; e += 4) {
        int s0 = csrc[e], s1 = csrc[e + 1], s2 = csrc[e + 2], s3 = csrc[e + 3];
        float2 x0 = *(const float2*)&XL[(size_t)s0 * D + f];
        float2 x1 = *(const float2*)&XL[(size_t)s1 * D + f];
        float2 x2 = *(const float2*)&XL[(size_t)s2 * D + f];
        float2 x3 = *(const float2*)&XL[(size_t)s3 * D + f];
        float vx, vy, p0, p1, p2, p3;
        vx = x0.x + xr.x; vy = x0.y + xr.y;
        p0 = fmaxf(vx, LRELU * vx) * at.x + fmaxf(vy, LRELU * vy) * at.y;
        vx = x1.x + xr.x; vy = x1.y + xr.y;
        p1 = fmaxf(vx, LRELU * vx) * at.x + fmaxf(vy, LRELU * vy) * at.y;
        vx = x2.x + xr.x; vy = x2.y + xr.y;
        p2 = fmaxf(vx, LRELU * vx) * at.x + fmaxf(vy, LRELU * vy) * at.y;
        vx = x3.x + xr.x; vy = x3.y + xr.y;
        p3 = fmaxf(vx, LRELU * vx) * at.x + fmaxf(vy, LRELU * vy) * at.y;
        #pragma unroll
        for (int o = 8; o >= 1; o >>= 1) {
            p0 += __shfl_xor(p0, o);
            p1 += __shfl_xor(p1, o);
            p2 += __shfl_xor(p2, o);
            p3 += __shfl_xor(p3, o);
        }
        float pmax = fmaxf(fmaxf(p0, p1), fmaxf(p2, p3));
        float nm = fmaxf(m, pmax);
        float so = __expf(m - nm);
        float w0 = __expf(p0 - nm), w1 = __expf(p1 - nm);
        float w2 = __expf(p2 - nm), w3 = __expf(p3 - nm);
        s = s * so + ((w0 + w1) + (w2 + w3));
        ax = ax * so + ((w0 * x0.x + w1 * x1.x) + (w2 * x2.x + w3 * x3.x));
        ay = ay * so + ((w0 * x0.y + w1 * x1.y) + (w2 * x2.y + w3 * x3.y));
        m = nm;
    }
    for (; e < e1; ++e) {
        int src = csrc[e];
        float2 x0 = *(const float2*)&XL[(size_t)src * D + f];
        float vx = x0.x + xr.x, vy = x0.y + xr.y;
        float p = fmaxf(vx, LRELU * vx) * at.x + fmaxf(vy, LRELU * vy) * at.y;
        #pragma unroll
        for (int o = 8; o >= 1; o >>= 1) p += __shfl_xor(p, o);
        float nm = fmaxf(m, p);
        float so = __expf(m - nm);
        float w  = __expf(p - nm);
        s = s * so + w;
        ax = ax * so + w * x0.x;
        ay = ay * so + w * x0.y;
        m = nm;
    }

    const float2 rs = *(const float2*)&RES[(size_t)i * D + f];
    const float2 bi = *(const float2*)&bias[f];
    float inv = 1.f / s;
    float rx = ax * inv + rs.x + bi.x;
    float ry = ay * inv + rs.y + bi.y;

    // LayerNorm over 128 features within the wave + ReLU
    float sum = rx + ry, sq = rx * rx + ry * ry;
    #pragma unroll
    for (int o = 32; o >= 1; o >>= 1) {
        sum += __shfl_xor(sum, o);
        sq  += __shfl_xor(sq, o);
    }
    float mu  = sum * (1.f / 128.f);
    float var = sq * (1.f / 128.f) - mu * mu;
    float isd = rsqrtf(var + LN_EPS);
    const float2 gv = *(const float2*)&g[f];
    const float2 bv = *(const float2*)&be[f];
    float2 o;
    o.x = fmaxf((rx - mu) * isd * gv.x + bv.x, 0.f);
    o.y = fmaxf((ry - mu) * isd * gv.y + bv.y, 0.f);
    *(float2*)&OUT[(size_t)i * D + f] = o;
}

// ---------------- launch ----------------

extern "C" void kernel_launch(void* const* d_in, const int* in_sizes, int n_in,
                              void* d_out, int out_size, void* d_ws, size_t ws_size,
                              hipStream_t stream)
{
    const float* x    = (const float*)d_in[0];
    const int*   ei   = (const int*)d_in[1];
    const float* Wl0  = (const float*)d_in[2];
    const float* bl0  = (const float*)d_in[3];
    const float* Wr0  = (const float*)d_in[4];
    const float* br0  = (const float*)d_in[5];
    const float* att0 = (const float*)d_in[6];
    const float* Wres0= (const float*)d_in[7];
    const float* bias0= (const float*)d_in[8];
    const float* g0   = (const float*)d_in[9];
    const float* be0  = (const float*)d_in[10];
    const float* Wl1  = (const float*)d_in[11];
    const float* bl1  = (const float*)d_in[12];
    const float* Wr1  = (const float*)d_in[13];
    const float* br1  = (const float*)d_in[14];
    const float* att1 = (const float*)d_in[15];
    const float* Wres1= (const float*)d_in[16];
    const float* bias1= (const float*)d_in[17];
    const float* g1   = (const float*)d_in[18];
    const float* be1  = (const float*)d_in[19];

    const int N = in_sizes[0] / D;
    const int E = in_sizes[1] / 2;
    const int E2 = E + N;
    const int nb = (N + SCB - 1) / SCB;

    char* w = (char*)d_ws;
    float* XL   = (float*)w; w += (size_t)N * D * 4;
    float* XR   = (float*)w; w += (size_t)N * D * 4;
    float* RES  = (float*)w; w += (size_t)N * D * 4;
    float* Hbuf = (float*)w; w += (size_t)N * D * 4;
    int* deg  = (int*)w; w += (size_t)N * 4;
    int* off  = (int*)w; w += (size_t)(N + 1) * 4;
    int* cur  = (int*)w; w += (size_t)N * 4;
    int* bsum = (int*)w; w += (size_t)nb * 4;
    int* csrc = (int*)w; w += (size_t)E2 * 4;

    const int* srcp = ei;
    const int* dstp = ei + E;

    hipMemsetAsync(deg, 0, (size_t)N * 4, stream);
    count_kernel<<<(E2 + 255) / 256, 256, 0, stream>>>(dstp, deg, E, N);
    partial_kernel<<<nb, SCB, 0, stream>>>(deg, bsum, N);
    scan_bsum_kernel<<<1, SCB, 0, stream>>>(bsum, nb);
    write_off_kernel<<<nb, SCB, 0, stream>>>(deg, bsum, off, cur, N);
    scatter_kernel<<<(E2 + 255) / 256, 256, 0, stream>>>(srcp, dstp, cur, csrc, E, N);

    dim3 ggrid((N + TM - 1) / TM, 3);

    gemm_fused<<<ggrid, 256, 0, stream>>>(x, N, Wl0, Wr0, Wres0, bl0, br0, XL, XR, RES);
    gat_node<<<(N + WPB - 1) / WPB, 64 * WPB, 0, stream>>>(XL, XR, RES, att0, bias0, g0, be0, off, csrc, Hbuf, N);
    gemm_fused<<<ggrid, 256, 0, stream>>>(Hbuf, N, Wl1, Wr1, Wres1, bl1, br1, XL, XR, RES);
    gat_node<<<(N + WPB - 1) / WPB, 64 * WPB, 0, stream>>>(XL, XR, RES, att1, bias1, g1, be1, off, csrc, (float*)d_out, N);
}

// Round 4
// 255.645 us; speedup vs baseline: 2.4800x; 1.4579x over previous
//
#include <hip/hip_runtime.h>
#include <math.h>

#define D 128
#define LRELU 0.2f
#define LN_EPS 1e-5f

typedef __attribute__((ext_vector_type(8))) short short8;
typedef __attribute__((ext_vector_type(4))) float f32x4;

static __device__ __forceinline__ unsigned short f2bf(float f) {
    union { float f; unsigned u; } a; a.f = f;
    unsigned r = a.u + 0x7FFFu + ((a.u >> 16) & 1u);
    return (unsigned short)(r >> 16);
}

// ---------------- CSR build (self-loops folded in: E' = E + N) ----------------

__global__ void count_kernel(const int* __restrict__ dst, int* __restrict__ deg, int E, int N) {
    int e = blockIdx.x * blockDim.x + threadIdx.x;
    if (e < E + N) atomicAdd(&deg[e < E ? dst[e] : e - E], 1);
}

#define SCB 256

__global__ __launch_bounds__(SCB) void partial_kernel(const int* __restrict__ deg,
                                                      int* __restrict__ bsum, int n) {
    int i = blockIdx.x * SCB + threadIdx.x;
    int v = (i < n) ? deg[i] : 0;
    #pragma unroll
    for (int o = 32; o >= 1; o >>= 1) v += __shfl_xor(v, o);
    __shared__ int ws[4];
    if ((threadIdx.x & 63) == 0) ws[threadIdx.x >> 6] = v;
    __syncthreads();
    if (threadIdx.x == 0) bsum[blockIdx.x] = ws[0] + ws[1] + ws[2] + ws[3];
}

__global__ __launch_bounds__(SCB) void scan_bsum_kernel(int* __restrict__ bsum, int nb) {
    int t = threadIdx.x;
    int v = (t < nb) ? bsum[t] : 0;
    int incl = v;
    #pragma unroll
    for (int o = 1; o < 64; o <<= 1) {
        int u = __shfl_up(incl, o);
        if ((t & 63) >= o) incl += u;
    }
    __shared__ int wp[4];
    if ((t & 63) == 63) wp[t >> 6] = incl;
    __syncthreads();
    int add = 0;
    for (int k = 0; k < (t >> 6); ++k) add += wp[k];
    incl += add;
    if (t < nb) bsum[t] = incl - v;
}

__global__ __launch_bounds__(SCB) void write_off_kernel(const int* __restrict__ deg,
                                                        const int* __restrict__ boff,
                                                        int* __restrict__ off,
                                                        int* __restrict__ cur, int n) {
    int t = threadIdx.x;
    int i = blockIdx.x * SCB + t;
    int v = (i < n) ? deg[i] : 0;
    int incl = v;
    #pragma unroll
    for (int o = 1; o < 64; o <<= 1) {
        int u = __shfl_up(incl, o);
        if ((t & 63) >= o) incl += u;
    }
    __shared__ int wp[4];
    if ((t & 63) == 63) wp[t >> 6] = incl;
    __syncthreads();
    int add = boff[blockIdx.x];
    for (int k = 0; k < (t >> 6); ++k) add += wp[k];
    int excl = add + incl - v;
    if (i < n) { off[i] = excl; cur[i] = excl; }
    if (i == n - 1) off[n] = excl + v;
}

__global__ void scatter_kernel(const int* __restrict__ src, const int* __restrict__ dst,
                               int* __restrict__ cur, int* __restrict__ csrc, int E, int N) {
    int e = blockIdx.x * blockDim.x + threadIdx.x;
    if (e < E + N) {
        int d  = (e < E) ? dst[e] : e - E;
        int sc = (e < E) ? src[e] : e - E;
        int p = atomicAdd(&cur[d], 1);
        csrc[p] = sc;
    }
}

// ---------------- fp32 -> bf16 convert (+ zero pad rows) ----------------

__global__ void convx_kernel(const float* __restrict__ X, ushort* __restrict__ Xb,
                             int M, int Mp) {
    int idx = blockIdx.x * 256 + threadIdx.x;       // one 4-elem group
    if (idx >= Mp * (D / 4)) return;
    ushort4 o;
    if (idx < M * (D / 4)) {
        float4 v = ((const float4*)X)[idx];
        o.x = f2bf(v.x); o.y = f2bf(v.y); o.z = f2bf(v.z); o.w = f2bf(v.w);
    } else {
        o = make_ushort4(0, 0, 0, 0);
    }
    ((ushort4*)Xb)[idx] = o;
}

// ---------------- pack W[k][col] fp32 -> MFMA B-fragment order bf16 ----------------
// Wp[m][kc][ct][lane][j] = W_m[kc*32 + (lane>>4)*8 + j][ct*16 + (lane&15)]

__global__ __launch_bounds__(256) void packw_kernel(
    const float* __restrict__ W0, const float* __restrict__ W1, const float* __restrict__ W2,
    const float* __restrict__ W3, const float* __restrict__ W4, const float* __restrict__ W5,
    ushort* __restrict__ Wp)
{
    int m = blockIdx.x >> 6;
    int o = ((blockIdx.x & 63) << 8) + threadIdx.x;   // 0..16383
    const float* W;
    if (m == 0) W = W0; else if (m == 1) W = W1; else if (m == 2) W = W2;
    else if (m == 3) W = W3; else if (m == 4) W = W4; else W = W5;
    int j  = o & 7;
    int l  = (o >> 3) & 63;
    int ct = (o >> 9) & 7;
    int kc = o >> 12;
    int k   = kc * 32 + ((l >> 4) << 3) + j;
    int col = (ct << 4) + (l & 15);
    Wp[m * 16384 + o] = f2bf(W[k * D + col]);
}

// ---------------- bf16 MFMA GEMM, no LDS: X @ [Wl|Wr|Wres] ----------------
// grid (Mp/128, 3); 256 thr = 4 waves as 2x2 of 64x64; K=128 in 4 chunks of 32.

__global__ __launch_bounds__(256) void gemm_mfma(
    const ushort* __restrict__ Xb, const ushort* __restrict__ Wp,
    const float* __restrict__ bl, const float* __restrict__ br,
    ushort* __restrict__ XLb, ushort* __restrict__ XRb, float* __restrict__ RES)
{
    const int seg = blockIdx.y;
    const int tid = threadIdx.x;
    const int l = tid & 63;
    const int wave = tid >> 6;
    const int wr = wave >> 1, wc = wave & 1;
    const int brow = blockIdx.x * 128 + wr * 64;
    const ushort* W = Wp + seg * 16384;

    f32x4 acc[4][4] = {};
    const int arow = brow + (l & 15);
    const int koff = (l >> 4) * 8;

    #pragma unroll
    for (int kc = 0; kc < 4; ++kc) {
        short8 A[4], B[4];
        #pragma unroll
        for (int at = 0; at < 4; ++at)
            A[at] = *(const short8*)&Xb[(size_t)(arow + at * 16) * D + kc * 32 + koff];
        #pragma unroll
        for (int ct = 0; ct < 4; ++ct) {
            int ctg = wc * 4 + ct;
            B[ct] = *(const short8*)&W[(((kc * 8 + ctg) * 64) + l) * 8];
        }
        #pragma unroll
        for (int at = 0; at < 4; ++at)
            #pragma unroll
            for (int ct = 0; ct < 4; ++ct)
                acc[at][ct] = __builtin_amdgcn_mfma_f32_16x16x32_bf16(A[at], B[ct], acc[at][ct], 0, 0, 0);
    }

    const int c = l & 15;
    const int r0 = (l >> 4) * 4;
    const float* bias = (seg == 0) ? bl : ((seg == 1) ? br : nullptr);
    #pragma unroll
    for (int ct = 0; ct < 4; ++ct) {
        int gcol = wc * 64 + ct * 16 + c;
        float bv = bias ? bias[gcol] : 0.f;
        #pragma unroll
        for (int at = 0; at < 4; ++at) {
            #pragma unroll
            for (int r = 0; r < 4; ++r) {
                int grow = brow + at * 16 + r0 + r;
                float v = acc[at][ct][r] + bv;
                size_t off = (size_t)grow * D + gcol;
                if (seg == 0)      XLb[off] = f2bf(v);
                else if (seg == 1) XRb[off] = f2bf(v);
                else               RES[off] = v;
            }
        }
    }
}

// ---------------- GATv2 aggregation + residual + LN + ReLU ----------------
// 2 nodes per wave: lane owns 4 channels (f=(l&31)*4); head = 8 lanes; 4-edge batches.

__global__ __launch_bounds__(256) void gat_node(
    const ushort* __restrict__ XLb, const ushort* __restrict__ XRb, const float* __restrict__ RES,
    const float* __restrict__ att, const float* __restrict__ bias,
    const float* __restrict__ g, const float* __restrict__ be,
    const int* __restrict__ off, const int* __restrict__ csrc,
    float* __restrict__ OUTf, ushort* __restrict__ OUTb)
{
    const int l = threadIdx.x & 63;
    const int i = blockIdx.x * 8 + (threadIdx.x >> 6) * 2 + (l >> 5);
    const int f = (l & 31) * 4;

    const float4 at4 = *(const float4*)&att[f];
    uint2 xru = *(const uint2*)&XRb[(size_t)i * D + f];
    const float xr0 = __uint_as_float(xru.x << 16);
    const float xr1 = __uint_as_float(xru.x & 0xFFFF0000u);
    const float xr2 = __uint_as_float(xru.y << 16);
    const float xr3 = __uint_as_float(xru.y & 0xFFFF0000u);

    const int e0 = off[i], e1 = off[i + 1];
    int len = e1 - e0;
    int mx = max(len, __shfl_xor(len, 32));
    int nb = (mx + 3) >> 2;

    float m = -1e30f, s = 0.f;
    float a0 = 0.f, a1 = 0.f, a2 = 0.f, a3 = 0.f;

    for (int b = 0; b < nb; ++b) {
        int base = e0 + b * 4;
        float p[4], x0[4], x1[4], x2[4], x3[4];
        #pragma unroll
        for (int j = 0; j < 4; ++j) {
            int ej = base + j;
            bool val = ej < e1;
            int sj = csrc[val ? ej : (e1 - 1)];
            uint2 u = *(const uint2*)&XLb[(size_t)sj * D + f];
            x0[j] = __uint_as_float(u.x << 16);
            x1[j] = __uint_as_float(u.x & 0xFFFF0000u);
            x2[j] = __uint_as_float(u.y << 16);
            x3[j] = __uint_as_float(u.y & 0xFFFF0000u);
            float v0 = x0[j] + xr0, v1 = x1[j] + xr1, v2 = x2[j] + xr2, v3 = x3[j] + xr3;
            float pj;
            pj  = fmaxf(v0, LRELU * v0) * at4.x;
            pj += fmaxf(v1, LRELU * v1) * at4.y;
            pj += fmaxf(v2, LRELU * v2) * at4.z;
            pj += fmaxf(v3, LRELU * v3) * at4.w;
            #pragma unroll
            for (int o = 4; o >= 1; o >>= 1) pj += __shfl_xor(pj, o);
            p[j] = val ? pj : -1e30f;
        }
        float pmax = fmaxf(fmaxf(p[0], p[1]), fmaxf(p[2], p[3]));
        float nm = fmaxf(m, pmax);
        float so = __expf(m - nm);
        float w0 = __expf(p[0] - nm), w1 = __expf(p[1] - nm);
        float w2 = __expf(p[2] - nm), w3 = __expf(p[3] - nm);
        s = s * so + ((w0 + w1) + (w2 + w3));
        a0 = a0 * so + ((w0 * x0[0] + w1 * x0[1]) + (w2 * x0[2] + w3 * x0[3]));
        a1 = a1 * so + ((w0 * x1[0] + w1 * x1[1]) + (w2 * x1[2] + w3 * x1[3]));
        a2 = a2 * so + ((w0 * x2[0] + w1 * x2[1]) + (w2 * x2[2] + w3 * x2[3]));
        a3 = a3 * so + ((w0 * x3[0] + w1 * x3[1]) + (w2 * x3[2] + w3 * x3[3]));
        m = nm;
    }

    const float4 rs = *(const float4*)&RES[(size_t)i * D + f];
    const float4 bi = *(const float4*)&bias[f];
    float inv = 1.f / s;
    float r0 = a0 * inv + rs.x + bi.x;
    float r1 = a1 * inv + rs.y + bi.y;
    float r2 = a2 * inv + rs.z + bi.z;
    float r3 = a3 * inv + rs.w + bi.w;

    // LayerNorm over 128 features (32 lanes) + ReLU
    float sum = (r0 + r1) + (r2 + r3);
    float sq  = (r0 * r0 + r1 * r1) + (r2 * r2 + r3 * r3);
    #pragma unroll
    for (int o = 16; o >= 1; o >>= 1) {
        sum += __shfl_xor(sum, o);
        sq  += __shfl_xor(sq, o);
    }
    float mu  = sum * (1.f / 128.f);
    float var = sq * (1.f / 128.f) - mu * mu;
    float isd = rsqrtf(var + LN_EPS);
    const float4 gv = *(const float4*)&g[f];
    const float4 bv = *(const float4*)&be[f];
    float o0 = fmaxf((r0 - mu) * isd * gv.x + bv.x, 0.f);
    float o1 = fmaxf((r1 - mu) * isd * gv.y + bv.y, 0.f);
    float o2 = fmaxf((r2 - mu) * isd * gv.z + bv.z, 0.f);
    float o3 = fmaxf((r3 - mu) * isd * gv.w + bv.w, 0.f);

    if (OUTb) {
        ushort4 ob = make_ushort4(f2bf(o0), f2bf(o1), f2bf(o2), f2bf(o3));
        *(ushort4*)&OUTb[(size_t)i * D + f] = ob;
    } else {
        float4 of = make_float4(o0, o1, o2, o3);
        *(float4*)&OUTf[(size_t)i * D + f] = of;
    }
}

// ---------------- launch ----------------

extern "C" void kernel_launch(void* const* d_in, const int* in_sizes, int n_in,
                              void* d_out, int out_size, void* d_ws, size_t ws_size,
                              hipStream_t stream)
{
    const float* x    = (const float*)d_in[0];
    const int*   ei   = (const int*)d_in[1];
    const float* Wl0  = (const float*)d_in[2];
    const float* bl0  = (const float*)d_in[3];
    const float* Wr0  = (const float*)d_in[4];
    const float* br0  = (const float*)d_in[5];
    const float* att0 = (const float*)d_in[6];
    const float* Wres0= (const float*)d_in[7];
    const float* bias0= (const float*)d_in[8];
    const float* g0   = (const float*)d_in[9];
    const float* be0  = (const float*)d_in[10];
    const float* Wl1  = (const float*)d_in[11];
    const float* bl1  = (const float*)d_in[12];
    const float* Wr1  = (const float*)d_in[13];
    const float* br1  = (const float*)d_in[14];
    const float* att1 = (const float*)d_in[15];
    const float* Wres1= (const float*)d_in[16];
    const float* bias1= (const float*)d_in[17];
    const float* g1   = (const float*)d_in[18];
    const float* be1  = (const float*)d_in[19];

    const int N  = in_sizes[0] / D;
    const int E  = in_sizes[1] / 2;
    const int E2 = E + N;
    const int nblk = (N + 127) / 128;     // 391
    const int Mp = nblk * 128;            // 50048
    const int nb = (N + SCB - 1) / SCB;

    char* w = (char*)d_ws;
    ushort* Xb  = (ushort*)w; w += (size_t)Mp * D * 2;
    ushort* Hb  = (ushort*)w; w += (size_t)Mp * D * 2;
    ushort* XLb = (ushort*)w; w += (size_t)Mp * D * 2;
    ushort* XRb = (ushort*)w; w += (size_t)Mp * D * 2;
    float*  RES = (float*)w;  w += (size_t)Mp * D * 4;
    ushort* Wp  = (ushort*)w; w += (size_t)6 * 16384 * 2;
    int* deg  = (int*)w; w += (size_t)N * 4;
    int* off  = (int*)w; w += (size_t)(N + 1) * 4;
    int* cur  = (int*)w; w += (size_t)N * 4;
    int* bsum = (int*)w; w += (size_t)nb * 4;
    int* csrc = (int*)w; w += (size_t)E2 * 4;

    const int* srcp = ei;
    const int* dstp = ei + E;

    // prep: bf16 convert + weight pack
    convx_kernel<<<(Mp * (D / 4) + 255) / 256, 256, 0, stream>>>(x, Xb, N, Mp);
    packw_kernel<<<6 * 64, 256, 0, stream>>>(Wl0, Wr0, Wres0, Wl1, Wr1, Wres1, Wp);

    // CSR by destination
    hipMemsetAsync(deg, 0, (size_t)N * 4, stream);
    count_kernel<<<(E2 + 255) / 256, 256, 0, stream>>>(dstp, deg, E, N);
    partial_kernel<<<nb, SCB, 0, stream>>>(deg, bsum, N);
    scan_bsum_kernel<<<1, SCB, 0, stream>>>(bsum, nb);
    write_off_kernel<<<nb, SCB, 0, stream>>>(deg, bsum, off, cur, N);
    scatter_kernel<<<(E2 + 255) / 256, 256, 0, stream>>>(srcp, dstp, cur, csrc, E, N);

    dim3 ggrid(nblk, 3);
    const int gatg = N / 8;   // 6250 exact

    // Layer 0
    gemm_mfma<<<ggrid, 256, 0, stream>>>(Xb, Wp, bl0, br0, XLb, XRb, RES);
    gat_node<<<gatg, 256, 0, stream>>>(XLb, XRb, RES, att0, bias0, g0, be0, off, csrc, nullptr, Hb);
    // Layer 1
    gemm_mfma<<<ggrid, 256, 0, stream>>>(Hb, Wp + 3 * 16384, bl1, br1, XLb, XRb, RES);
    gat_node<<<gatg, 256, 0, stream>>>(XLb, XRb, RES, att1, bias1, g1, be1, off, csrc, (float*)d_out, nullptr);
}